// Round 8
// baseline (280.751 us; speedup 1.0000x reference)
//
#include <hip/hip_runtime.h>
#include <hip/hip_bf16.h>
#include <cmath>

#define H 256
#define W 256
#define NIMG 64
#define HW 65536
#define NBLK 2048
#define NWAVE (NBLK * 4)      // 8192 waves; tasks = 64*8*256 = 131072 = NWAVE*16

typedef float vf4 __attribute__((ext_vector_type(4)));   // native vector for nontemporal builtins

// ---------- reduction helpers (wave64) ----------
__device__ inline float waveReduceSum(float v) {
#pragma unroll
    for (int o = 32; o > 0; o >>= 1) v += __shfl_xor(v, o, 64);
    return v;
}
__device__ inline float waveReduceMax(float v) {
#pragma unroll
    for (int o = 32; o > 0; o >>= 1) v = fmaxf(v, __shfl_xor(v, o, 64));
    return v;
}
__device__ inline float blockReduceSum(float v, float* s) {
    int lane = threadIdx.x & 63, wv = threadIdx.x >> 6;
    v = waveReduceSum(v);
    if (lane == 0) s[wv] = v;
    __syncthreads();
    float r = 0.f;
    if (wv == 0) {
        r = (lane < 4) ? s[lane] : 0.f;
        r = waveReduceSum(r);
    }
    __syncthreads();
    return r;
}

// ---------- kernel 1: sigma = sigmoid(src) + row/col maxes ----------
__global__ __launch_bounds__(256) void k_prep(
    const float* __restrict__ src, const int* __restrict__ bm,
    float* __restrict__ sigma,
    float* __restrict__ colpart_x, float* __restrict__ colpart_b,
    float* __restrict__ rowmax_x, float* __restrict__ rowmax_b)
{
    __shared__ float sx[32][4];
    __shared__ float sb[32][4];
    const int chunk = blockIdx.x, n = blockIdx.y, t = threadIdx.x;
    const int lane = t & 63, wv = t >> 6;
    const size_t base = (size_t)n * HW + chunk * 32 * W + t;
    const float* s = src + base;
    const int* b = bm + base;
    float* sg = sigma + base;
    float mx = -3.4e38f, mb = 0.f;
#pragma unroll 4
    for (int r = 0; r < 32; r++) {
        const float x = s[r * W];
        const float bf = (float)b[r * W];
        sg[r * W] = __builtin_amdgcn_rcpf(1.f + __expf(-x));
        mx = fmaxf(mx, x);
        mb = fmaxf(mb, bf);
        const float rx = waveReduceMax(x);
        const float rb = waveReduceMax(bf);
        if (lane == 0) { sx[r][wv] = rx; sb[r][wv] = rb; }
    }
    const int o = (n * 8 + chunk) * W + t;
    colpart_x[o] = mx;
    colpart_b[o] = mb;
    __syncthreads();
    if (t < 32) {
        rowmax_x[n * H + chunk * 32 + t] =
            fmaxf(fmaxf(sx[t][0], sx[t][1]), fmaxf(sx[t][2], sx[t][3]));
    } else if (t < 64) {
        const int r = t - 32;
        rowmax_b[n * H + chunk * 32 + r] =
            fmaxf(fmaxf(sb[r][0], sb[r][1]), fmaxf(sb[r][2], sb[r][3]));
    }
}

// ---------- kernel 2: plane-decomposed pairwise, linear streaming ----------
// st = sum_p sum_px bm*sel_p*(-log P_p); P = sc*sn+(1-sc)(1-sn).
// Wave wid owns fixed (h,p), sweeps n = n0 + 4k, k=0..15 -> ts read linearly.
__global__ __launch_bounds__(256, 4) void k_stream(
    const float* __restrict__ ts, const int* __restrict__ bm,
    const float* __restrict__ sigma,
    float* __restrict__ part_st, float* __restrict__ part_t)
{
    const int t = threadIdx.x, lane = t & 63, wv = t >> 6;
    const int wid = blockIdx.x * 4 + wv;          // 0..8191
    const int c0 = lane << 2;
    const int lm = (lane + 63) & 63, lp = (lane + 1) & 63;

    const int h  = wid & 255;
    const int p  = (wid >> 8) & 7;
    const int n0 = wid >> 11;                     // 0..3

    const int DR = (p < 3) ? -2 : ((p < 5) ? 0 : 2);
    const int DC = (p == 0 || p == 3 || p == 5) ? -2 : ((p == 1 || p == 6) ? 0 : 2);
    const int hn = h + DR;
    const bool rv = (hn >= 0) && (hn < H);
    const int hnc = rv ? hn : h;

    const float* tsp0 = ts + ((size_t)(n0 * 8 + p)) * HW + (size_t)h * W + c0;
    const int*   bmp0 = bm + (size_t)n0 * HW + (size_t)h * W + c0;
    const float* scp0 = sigma + (size_t)n0 * HW + (size_t)h * W + c0;
    const float* snp0 = sigma + (size_t)n0 * HW + (size_t)hnc * W + c0;
    const size_t tstride = (size_t)4 * 8 * HW;    // 4 images of ts
    const size_t istride = (size_t)4 * HW;        // 4 images of src/bm

    float st = 0.f, tt = 0.f;

    vf4 Ats = __builtin_nontemporal_load(reinterpret_cast<const vf4*>(tsp0));
    int4   Abm = *reinterpret_cast<const int4*>(bmp0);
    float4 Asc = *reinterpret_cast<const float4*>(scp0);
    float4 Asn = *reinterpret_cast<const float4*>(snp0);

#pragma unroll 1
    for (int k = 0; k < 16; k++) {
        vf4 Bts = Ats; int4 Bbm = Abm; float4 Bsc = Asc; float4 Bsn = Asn;
        if (k < 15) {
            Bts = __builtin_nontemporal_load(
                reinterpret_cast<const vf4*>(tsp0 + (size_t)(k + 1) * tstride));
            Bbm = *reinterpret_cast<const int4*>(bmp0 + (size_t)(k + 1) * istride);
            Bsc = *reinterpret_cast<const float4*>(scp0 + (size_t)(k + 1) * istride);
            Bsn = *reinterpret_cast<const float4*>(snp0 + (size_t)(k + 1) * istride);
        }
        // consume A
        const float win[8] = {
            __shfl(Asn.z, lm, 64), __shfl(Asn.w, lm, 64),
            Asn.x, Asn.y, Asn.z, Asn.w,
            __shfl(Asn.x, lp, 64), __shfl(Asn.y, lp, 64)
        };
        const float scv[4] = {Asc.x, Asc.y, Asc.z, Asc.w};
        const float tsv[4] = {Ats.x, Ats.y, Ats.z, Ats.w};
        const int   bmv[4] = {Abm.x, Abm.y, Abm.z, Abm.w};
        float prod = 1.f;
#pragma unroll
        for (int i = 0; i < 4; i++) {
            const float sc = scv[i];
            const float bmf = (float)bmv[i];
            const bool thr = (tsv[i] >= 0.3f);
            tt += thr ? bmf : 0.f;
            const int col = c0 + i + DC;
            const bool valid = rv && (col >= 0) && (col < W);
            const float sn = (DC == -2) ? win[i] : ((DC == 0) ? win[i + 2] : win[i + 4]);
            const float P = fmaf(2.f * sc, sn, (1.f - sc) - sn);
            prod *= (thr && valid && (bmv[i] != 0)) ? P : 1.f;
        }
        st -= __logf(prod);
        Ats = Bts; Abm = Bbm; Asc = Bsc; Asn = Bsn;
    }
    const float wst = waveReduceSum(st);
    const float wtt = waveReduceSum(tt);
    if (lane == 0) { part_st[wid] = wst; part_t[wid] = wtt; }
}

// ---------- kernel 3: per-image projection loss ----------
__global__ __launch_bounds__(256) void k_proj(
    const float* __restrict__ colpart_x, const float* __restrict__ colpart_b,
    const float* __restrict__ rowmax_x, const float* __restrict__ rowmax_b,
    float* __restrict__ proj)
{
    __shared__ float red[4];
    const int n = blockIdx.x, t = threadIdx.x;
    float cx = -3.4e38f, cb = 0.f;
#pragma unroll
    for (int c = 0; c < 8; c++) {
        cx = fmaxf(cx, colpart_x[(n * 8 + c) * W + t]);
        cb = fmaxf(cb, colpart_b[(n * 8 + c) * W + t]);
    }
    const float iy = 1.f / (1.f + expf(-cx));
    const float ty = cb;
    const float ix = 1.f / (1.f + expf(-rowmax_x[n * H + t]));
    const float tx = rowmax_b[n * H + t];

    const float Sxy = blockReduceSum(ix * tx, red);
    const float Sxx = blockReduceSum(ix * ix, red);
    const float Stx = blockReduceSum(tx * tx, red);
    const float Syw = blockReduceSum(iy * ty, red);
    const float Syy = blockReduceSum(iy * iy, red);
    const float Sty = blockReduceSum(ty * ty, red);
    if (t == 0) {
        const float eps = 0.001f;
        const float lx = 1.f - 2.f * Sxy / (Sxx + Stx + eps);
        const float ly = 1.f - 2.f * Syw / (Syy + Sty + eps);
        proj[n] = lx + ly;
    }
}

// ---------- kernel 4: CE + final combine ----------
__global__ __launch_bounds__(256) void k_final(
    const float* __restrict__ logits, const int* __restrict__ tcls,
    const float* __restrict__ ew, const int* __restrict__ num_masks,
    const float* __restrict__ part_st, const float* __restrict__ part_t,
    const float* __restrict__ proj, float* __restrict__ out)
{
    __shared__ float red[4];
    const int t = threadIdx.x;
    float s1 = 0.f, s2 = 0.f;
    for (int i = t; i < NWAVE; i += 256) { s1 += part_st[i]; s2 += part_t[i]; }
    const float sum_st = blockReduceSum(s1, red);
    const float sum_t = blockReduceSum(s2, red);
    const float pj = (t < NIMG) ? proj[t] : 0.f;
    const float sum_pj = blockReduceSum(pj, red);

    float wn = 0.f, wsum = 0.f;
    if (t < 200) {
        const float* row = logits + t * 81;
        float mx = -3.4e38f;
        for (int c = 0; c < 81; c++) mx = fmaxf(mx, row[c]);
        float se = 0.f;
        for (int c = 0; c < 81; c++) se += expf(row[c] - mx);
        const float lse = mx + logf(se);
        const int tc = tcls[t];
        const float nll = lse - row[tc];
        const float wv = ew[tc];
        wn = wv * nll;
        wsum = wv;
    }
    const float Swn = blockReduceSum(wn, red);
    const float Sw = blockReduceSum(wsum, red);
    if (t == 0) {
        const float nm = (float)max(num_masks[0], 1);
        const float loss_ce = Swn / Sw;
        const float loss_pw = sum_st / fmaxf(sum_t, 1.f) / nm;
        const float loss_pj = sum_pj / nm;
        out[0] = loss_ce + loss_pw + loss_pj;
    }
}

extern "C" void kernel_launch(void* const* d_in, const int* in_sizes, int n_in,
                              void* d_out, int out_size, void* d_ws, size_t ws_size,
                              hipStream_t stream) {
    const float* pred_logits = (const float*)d_in[0];  // [2,100,81]
    const float* src         = (const float*)d_in[1];  // [64,256,256]
    const float* ew          = (const float*)d_in[2];  // [81]
    const float* ts          = (const float*)d_in[3];  // [64,8,256,256]
    const int*   tcls        = (const int*)d_in[4];    // [2,100]
    const int*   bm          = (const int*)d_in[5];    // [64,256,256]
    const int*   nmasks      = (const int*)d_in[6];    // [1]
    float* out = (float*)d_out;

    float* ws = (float*)d_ws;
    float* sigma     = ws;                 // 4,194,304
    float* part_st   = ws + 4194304;       // 8192
    float* part_t    = ws + 4202496;       // 8192
    float* rowmax_x  = ws + 4210688;       // 16384
    float* rowmax_b  = ws + 4227072;       // 16384
    float* colpart_x = ws + 4243456;       // 131072
    float* colpart_b = ws + 4374528;       // 131072
    float* proj      = ws + 4505600;       // 64

    k_prep<<<dim3(8, NIMG), 256, 0, stream>>>(src, bm, sigma,
                                              colpart_x, colpart_b, rowmax_x, rowmax_b);
    k_stream<<<NBLK, 256, 0, stream>>>(ts, bm, sigma, part_st, part_t);
    k_proj<<<NIMG, 256, 0, stream>>>(colpart_x, colpart_b, rowmax_x, rowmax_b, proj);
    k_final<<<1, 256, 0, stream>>>(pred_logits, tcls, ew, nmasks, part_st, part_t, proj, out);
}

// Round 9
// 277.775 us; speedup vs baseline: 1.0107x; 1.0107x over previous
//
#include <hip/hip_runtime.h>
#include <hip/hip_bf16.h>
#include <cmath>

#define H 256
#define W 256
#define NIMG 64
#define HW 65536
#define NSBLK 2048            // k_stream blocks: n(64) * p(8) * q(4)
#define NWAVE (NSBLK * 4)     // 8192 per-wave partials
#define NSTRIP 16             // column-partial strips per image (16 rows each)

typedef float vf4 __attribute__((ext_vector_type(4)));

// ---------- reduction helpers (wave64) ----------
__device__ inline float waveReduceSum(float v) {
#pragma unroll
    for (int o = 32; o > 0; o >>= 1) v += __shfl_xor(v, o, 64);
    return v;
}
__device__ inline float waveReduceMax(float v) {
#pragma unroll
    for (int o = 32; o > 0; o >>= 1) v = fmaxf(v, __shfl_xor(v, o, 64));
    return v;
}
__device__ inline float blockReduceSum(float v, float* s) {
    int lane = threadIdx.x & 63, wv = threadIdx.x >> 6;
    v = waveReduceSum(v);
    if (lane == 0) s[wv] = v;
    __syncthreads();
    float r = 0.f;
    if (wv == 0) {
        r = (lane < 4) ? s[lane] : 0.f;
        r = waveReduceSum(r);
    }
    __syncthreads();
    return r;
}

// ---------- kernel 1: sigma = sigmoid(src), pure linear stream ----------
__global__ __launch_bounds__(256) void k_prep(
    const float* __restrict__ src, float* __restrict__ sigma)
{
    const vf4* s = reinterpret_cast<const vf4*>(src);
    vf4* g = reinterpret_cast<vf4*>(sigma);
    int i = blockIdx.x * 256 + threadIdx.x;          // 1024 blocks
#pragma unroll
    for (int k = 0; k < 4; k++) {                    // 4 * 262144 = 1,048,576 float4
        vf4 x = s[i];
        vf4 r;
        r.x = __builtin_amdgcn_rcpf(1.f + __expf(-x.x));
        r.y = __builtin_amdgcn_rcpf(1.f + __expf(-x.y));
        r.z = __builtin_amdgcn_rcpf(1.f + __expf(-x.z));
        r.w = __builtin_amdgcn_rcpf(1.f + __expf(-x.w));
        g[i] = r;
        i += 262144;
    }
}

// ---------- kernel 2: plane-linear pairwise + maxes (p==1 blocks) ----------
// Wave streams 16 contiguous rows of ONE ts plane (16 KB sequential run).
// st = sum_p sum_px bm*sel_p*(-log P_p); P = sc*sn + (1-sc)(1-sn).
__global__ __launch_bounds__(256) void k_stream(
    const float* __restrict__ ts, const int* __restrict__ bm,
    const float* __restrict__ sigma,
    float* __restrict__ part_st, float* __restrict__ part_t,
    float* __restrict__ rowsig, float* __restrict__ rowmax_b,
    float* __restrict__ colpart_s, float* __restrict__ colpart_b)
{
    const int t = threadIdx.x, lane = t & 63, wv = t >> 6;
    const int blk = blockIdx.x;                   // n*32 + p*4 + q
    const int q = blk & 3, p = (blk >> 2) & 7, n = blk >> 5;
    const int h0 = q * 64 + wv * 16;
    const int c0 = lane << 2;
    const int lm = (lane + 63) & 63, lp = (lane + 1) & 63;
    const int DR = (p < 3) ? -2 : ((p < 5) ? 0 : 2);
    const int DC = (p == 0 || p == 3 || p == 5) ? -2 : ((p == 1 || p == 6) ? 0 : 2);

    const float* tsp = ts + (size_t)(n * 8 + p) * HW;
    const int*   bmn = bm + (size_t)n * HW;
    const float* sgn = sigma + (size_t)n * HW;

    float st = 0.f, tt = 0.f;
    float cms[4] = {0.f, 0.f, 0.f, 0.f};
    float cmb[4] = {0.f, 0.f, 0.f, 0.f};

    float4 Ats, Asc, Asn; int4 Abm;
    {
        const int h = h0, hnc = min(max(h + DR, 0), H - 1);
        Ats = *reinterpret_cast<const float4*>(tsp + h * W + c0);
        Abm = *reinterpret_cast<const int4*>(bmn + h * W + c0);
        Asc = *reinterpret_cast<const float4*>(sgn + h * W + c0);
        Asn = *reinterpret_cast<const float4*>(sgn + hnc * W + c0);
    }
#pragma unroll 1
    for (int j = 0; j < 16; j++) {
        const int h = h0 + j;
        float4 Bts = Ats, Bsc = Asc, Bsn = Asn; int4 Bbm = Abm;
        if (j < 15) {
            const int h2 = h + 1, hnc2 = min(max(h2 + DR, 0), H - 1);
            Bts = *reinterpret_cast<const float4*>(tsp + h2 * W + c0);
            Bbm = *reinterpret_cast<const int4*>(bmn + h2 * W + c0);
            Bsc = *reinterpret_cast<const float4*>(sgn + h2 * W + c0);
            Bsn = *reinterpret_cast<const float4*>(sgn + hnc2 * W + c0);
        }
        const bool rv = (unsigned)(h + DR) < (unsigned)H;
        float win[4];
        if (DC == -2) {
            win[0] = __shfl(Asn.z, lm, 64); win[1] = __shfl(Asn.w, lm, 64);
            win[2] = Asn.x; win[3] = Asn.y;
        } else if (DC == 0) {
            win[0] = Asn.x; win[1] = Asn.y; win[2] = Asn.z; win[3] = Asn.w;
        } else {
            win[0] = Asn.z; win[1] = Asn.w;
            win[2] = __shfl(Asn.x, lp, 64); win[3] = __shfl(Asn.y, lp, 64);
        }
        const float scv[4] = {Asc.x, Asc.y, Asc.z, Asc.w};
        const float tsv[4] = {Ats.x, Ats.y, Ats.z, Ats.w};
        const int   bmv[4] = {Abm.x, Abm.y, Abm.z, Abm.w};
        float prod = 1.f;
#pragma unroll
        for (int i = 0; i < 4; i++) {
            const float sc = scv[i];
            const float bmf = (float)bmv[i];
            const bool thr = (tsv[i] >= 0.3f);
            tt += thr ? bmf : 0.f;
            const int col = c0 + i + DC;
            const bool valid = rv && ((unsigned)col < (unsigned)W);
            const float P = fmaf(2.f * sc, win[i], (1.f - sc) - win[i]);
            prod *= (thr && valid && (bmv[i] != 0)) ? P : 1.f;
            if (p == 1) { cms[i] = fmaxf(cms[i], sc); cmb[i] = fmaxf(cmb[i], bmf); }
        }
        st -= __logf(prod);
        if (p == 1) {   // exactly one p==1 wave owns each (n,h): do row maxes here
            const float m4s = fmaxf(fmaxf(scv[0], scv[1]), fmaxf(scv[2], scv[3]));
            const float m4b = fmaxf(fmaxf((float)bmv[0], (float)bmv[1]),
                                    fmaxf((float)bmv[2], (float)bmv[3]));
            const float wms = waveReduceMax(m4s);
            const float wmb = waveReduceMax(m4b);
            if (lane == 0) { rowsig[n * H + h] = wms; rowmax_b[n * H + h] = wmb; }
        }
        Ats = Bts; Abm = Bbm; Asc = Bsc; Asn = Bsn;
    }
    if (p == 1) {       // column partials for this 16-row strip
        const int sidx = q * 4 + wv;                 // 0..15
        const int co = (n * NSTRIP + sidx) * W + c0;
        *reinterpret_cast<float4*>(&colpart_s[co]) = make_float4(cms[0], cms[1], cms[2], cms[3]);
        *reinterpret_cast<float4*>(&colpart_b[co]) = make_float4(cmb[0], cmb[1], cmb[2], cmb[3]);
    }
    const float wst = waveReduceSum(st);
    const float wtt = waveReduceSum(tt);
    if (lane == 0) { const int wid = blk * 4 + wv; part_st[wid] = wst; part_t[wid] = wtt; }
}

// ---------- kernel 3: per-image projection loss ----------
__global__ __launch_bounds__(256) void k_proj(
    const float* __restrict__ colpart_s, const float* __restrict__ colpart_b,
    const float* __restrict__ rowsig, const float* __restrict__ rowmax_b,
    float* __restrict__ proj)
{
    __shared__ float red[4];
    const int n = blockIdx.x, t = threadIdx.x;
    float cs = 0.f, cb = 0.f;
#pragma unroll
    for (int c = 0; c < NSTRIP; c++) {
        cs = fmaxf(cs, colpart_s[(n * NSTRIP + c) * W + t]);
        cb = fmaxf(cb, colpart_b[(n * NSTRIP + c) * W + t]);
    }
    const float iy = cs;                  // sigma-space (monotone)
    const float ty = cb;
    const float ix = rowsig[n * H + t];
    const float tx = rowmax_b[n * H + t];

    const float Sxy = blockReduceSum(ix * tx, red);
    const float Sxx = blockReduceSum(ix * ix, red);
    const float Stx = blockReduceSum(tx * tx, red);
    const float Syw = blockReduceSum(iy * ty, red);
    const float Syy = blockReduceSum(iy * iy, red);
    const float Sty = blockReduceSum(ty * ty, red);
    if (t == 0) {
        const float eps = 0.001f;
        const float lx = 1.f - 2.f * Sxy / (Sxx + Stx + eps);
        const float ly = 1.f - 2.f * Syw / (Syy + Sty + eps);
        proj[n] = lx + ly;
    }
}

// ---------- kernel 4: CE + final combine ----------
__global__ __launch_bounds__(256) void k_final(
    const float* __restrict__ logits, const int* __restrict__ tcls,
    const float* __restrict__ ew, const int* __restrict__ num_masks,
    const float* __restrict__ part_st, const float* __restrict__ part_t,
    const float* __restrict__ proj, float* __restrict__ out)
{
    __shared__ float red[4];
    const int t = threadIdx.x;
    float s1 = 0.f, s2 = 0.f;
    for (int i = t; i < NWAVE; i += 256) { s1 += part_st[i]; s2 += part_t[i]; }
    const float sum_st = blockReduceSum(s1, red);
    const float sum_t = blockReduceSum(s2, red);
    const float pj = (t < NIMG) ? proj[t] : 0.f;
    const float sum_pj = blockReduceSum(pj, red);

    float wn = 0.f, wsum = 0.f;
    if (t < 200) {
        const float* row = logits + t * 81;
        float mx = -3.4e38f;
        for (int c = 0; c < 81; c++) mx = fmaxf(mx, row[c]);
        float se = 0.f;
        for (int c = 0; c < 81; c++) se += expf(row[c] - mx);
        const float lse = mx + logf(se);
        const int tc = tcls[t];
        const float nll = lse - row[tc];
        const float wv = ew[tc];
        wn = wv * nll;
        wsum = wv;
    }
    const float Swn = blockReduceSum(wn, red);
    const float Sw = blockReduceSum(wsum, red);
    if (t == 0) {
        const float nm = (float)max(num_masks[0], 1);
        const float loss_ce = Swn / Sw;
        const float loss_pw = sum_st / fmaxf(sum_t, 1.f) / nm;
        const float loss_pj = sum_pj / nm;
        out[0] = loss_ce + loss_pw + loss_pj;
    }
}

extern "C" void kernel_launch(void* const* d_in, const int* in_sizes, int n_in,
                              void* d_out, int out_size, void* d_ws, size_t ws_size,
                              hipStream_t stream) {
    const float* pred_logits = (const float*)d_in[0];  // [2,100,81]
    const float* src         = (const float*)d_in[1];  // [64,256,256]
    const float* ew          = (const float*)d_in[2];  // [81]
    const float* ts          = (const float*)d_in[3];  // [64,8,256,256]
    const int*   tcls        = (const int*)d_in[4];    // [2,100]
    const int*   bm          = (const int*)d_in[5];    // [64,256,256]
    const int*   nmasks      = (const int*)d_in[6];    // [1]
    float* out = (float*)d_out;

    float* ws = (float*)d_ws;
    float* sigma     = ws;                 // 4,194,304
    float* part_st   = ws + 4194304;       // 8192
    float* part_t    = ws + 4202496;       // 8192
    float* rowsig    = ws + 4210688;       // 16384
    float* rowmax_b  = ws + 4227072;       // 16384
    float* colpart_s = ws + 4243456;       // 64*16*256 = 262144
    float* colpart_b = ws + 4505600;       // 262144
    float* proj      = ws + 4767744;       // 64

    k_prep<<<1024, 256, 0, stream>>>(src, sigma);
    k_stream<<<NSBLK, 256, 0, stream>>>(ts, bm, sigma, part_st, part_t,
                                        rowsig, rowmax_b, colpart_s, colpart_b);
    k_proj<<<NIMG, 256, 0, stream>>>(colpart_s, colpart_b, rowsig, rowmax_b, proj);
    k_final<<<1, 256, 0, stream>>>(pred_logits, tcls, ew, nmasks, part_st, part_t, proj, out);
}